// Round 3
// baseline (365.400 us; speedup 1.0000x reference)
//
#include <hip/hip_runtime.h>
#include <hip/hip_bf16.h>

// Problem constants
#define B_    8
#define T_    4096
#define D_    1024
#define S_    64
#define NQ_   8
#define QDIM_ 256
#define TB_   64            // t-rows per partial-sum block
#define NTC_  (T_/TB_)      // 64 chunks
#define NBLK  512           // k_main grid; all co-resident (2/CU) or rotate safely

typedef __attribute__((ext_vector_type(4))) unsigned short u16x4;
typedef __attribute__((ext_vector_type(8))) unsigned short u16x8;
typedef __attribute__((ext_vector_type(4))) float f32x4;

__device__ __forceinline__ float b2f(unsigned short u) {
    union { unsigned int i; float f; } v; v.i = ((unsigned int)u) << 16; return v.f;
}
__device__ __forceinline__ unsigned short f2b(float f) {
    __hip_bfloat16 h = __float2bfloat16(f);   // RNE
    return *reinterpret_cast<unsigned short*>(&h);
}

// LDS-tree block reductions, 256 threads, buf is 256-float scratch.
__device__ __forceinline__ float blockSum(float v, float* buf) {
    int tid = threadIdx.x;
    buf[tid] = v; __syncthreads();
    #pragma unroll
    for (int s = 128; s > 0; s >>= 1) { if (tid < s) buf[tid] += buf[tid + s]; __syncthreads(); }
    float r = buf[0]; __syncthreads();
    return r;
}
__device__ __forceinline__ float blockMax(float v, float* buf) {
    int tid = threadIdx.x;
    buf[tid] = v; __syncthreads();
    #pragma unroll
    for (int s = 128; s > 0; s >>= 1) { if (tid < s) buf[tid] = fmaxf(buf[tid], buf[tid + s]); __syncthreads(); }
    float r = buf[0]; __syncthreads();
    return r;
}

// Per-block dtype detection: 256 threads sample 256 u16 words (same 512 B for
// every block -> L2/L3 broadcast). bf16 buffers decode ~256/256 plausible; the
// lo-halves of f32 words have random mantissa bits -> ~143/256.
__device__ __forceinline__ bool detect_f32(const unsigned short* __restrict__ p,
                                           unsigned elo, unsigned ehi, int* cnt) {
    int tid = threadIdx.x;
    if (tid == 0) *cnt = 0;
    __syncthreads();
    unsigned short u = p[tid];
    unsigned e = (u >> 7) & 0xFF;
    bool ok = ((u & 0x7FFF) == 0) || (e >= elo && e <= ehi);
    unsigned long long bm = __ballot(ok);
    if ((tid & 63) == 0) atomicAdd(cnt, (int)__popcll(bm));
    __syncthreads();
    bool isf32 = (*cnt < 200);
    __syncthreads();
    return isf32;
}

// Point-to-point producer/consumer flags (slots zeroed by hipMemsetAsync each
// launch). arrive: all prior stores of this block ordered by __syncthreads +
// release RMW (L2 writeback on this XCD). wait: relaxed poll (no cache
// maintenance) + single acquire load (L1/L2 inv) once satisfied.
__device__ __forceinline__ void arrive(int* slot) {
    __syncthreads();
    if (threadIdx.x == 0)
        __hip_atomic_fetch_add(slot, 1, __ATOMIC_RELEASE, __HIP_MEMORY_SCOPE_AGENT);
}
__device__ __forceinline__ void wait_for(int* slot, int target) {
    if (threadIdx.x == 0) {
        while (__hip_atomic_load(slot, __ATOMIC_RELAXED, __HIP_MEMORY_SCOPE_AGENT) < target)
            __builtin_amdgcn_s_sleep(1);
        (void)__hip_atomic_load(slot, __ATOMIC_ACQUIRE, __HIP_MEMORY_SCOPE_AGENT);
    }
    __syncthreads();
}

// Shared-memory union across phases. MPS no longer stages mid cores in LDS
// (reads them through L1) -> union is ~4.3 KB -> no occupancy impact.
struct LogitsSh { float xs2[256]; float xs[128]; };
struct SmSh     { float qa[QDIM_]; float buf[256]; };
struct MpsSh {
    float lcf[64];
    float lcl[64];
    float res[8][33];
    float nres[8][33];
    float lm0[64], lm1[64];
    float buf[256];
};
struct AttSh    { float att[S_]; float g[NQ_]; };
union Sh { LogitsSh lg; SmSh sm; MpsSh mps; AttSh att; };

// K1: colsum (all 512 blocks) + role-block DAG with point-to-point waits.
//   roles: blocks 0-63 logits partials; 64-127 wdred slices (no wait);
//          128-135 softmax+amp; 192-255 MPS per slot; 256-263 attention+proj.
// counters: c0 colsum(512), c1 plog(64), c2 m(8), c3 end(64 ovl + 64 wdred = 128)
__global__ __launch_bounds__(256, 2)
void k_main(const void* __restrict__ x,  const void* __restrict__ Wq,
            const void* __restrict__ bq, const void* __restrict__ Wd,
            const void* __restrict__ bd, const void* __restrict__ cf,
            const void* __restrict__ cm, const void* __restrict__ cl,
            float* __restrict__ partials, float* __restrict__ plog,
            float* __restrict__ sm0m, float* __restrict__ sm1m,
            float* __restrict__ feats, float* __restrict__ ovl,
            float* __restrict__ read_proj, float* __restrict__ wdred,
            int* __restrict__ c) {
    __shared__ Sh u;
    __shared__ int cnt;
    const int blk = blockIdx.x;
    const int tid = threadIdx.x;

    bool xf32 = detect_f32((const unsigned short*)x, 100, 130, &cnt);  // |v| in [2^-27,16)
    bool wf32 = detect_f32((const unsigned short*)Wq, 96, 126, &cnt);  // |v| in [2^-31,0.5)

    // ---- colsum chunk (every block)
    {
        int b  = blk >> 6;
        int tc = blk & 63;
        size_t base = ((size_t)(b * T_ + tc * TB_)) * D_ + tid * 4;
        float a0 = 0.f, a1 = 0.f, a2 = 0.f, a3 = 0.f;
        if (xf32) {
            const float* px = (const float*)x + base;
            #pragma unroll 8
            for (int i = 0; i < TB_; ++i) {
                f32x4 v = *reinterpret_cast<const f32x4*>(px + (size_t)i * D_);
                a0 += v[0]; a1 += v[1]; a2 += v[2]; a3 += v[3];
            }
        } else {
            const unsigned short* px = (const unsigned short*)x + base;
            #pragma unroll 8
            for (int i = 0; i < TB_; ++i) {
                u16x4 v = *reinterpret_cast<const u16x4*>(px + (size_t)i * D_);
                a0 += b2f(v[0]); a1 += b2f(v[1]); a2 += b2f(v[2]); a3 += b2f(v[3]);
            }
        }
        float* dst = partials + ((size_t)(tc * B_ + b)) * D_ + tid * 4;
        f32x4 r; r[0] = a0; r[1] = a1; r[2] = a2; r[3] = a3;
        *reinterpret_cast<f32x4*>(dst) = r;
    }
    arrive(c + 0);

    if (blk < 64) {
        // ---- logits partials: b = blk>>3, dc = blk&7
        wait_for(c + 0, NBLK);
        int b = blk >> 3, dc = blk & 7;
        int d0 = dc * 128;
        float a = 0.f;
        for (int tc = (tid >> 7); tc < NTC_; tc += 2)
            a += partials[((size_t)(tc * B_ + b)) * D_ + d0 + (tid & 127)];
        u.lg.xs2[tid] = a;
        __syncthreads();
        if (tid < 128) u.lg.xs[tid] = (u.lg.xs2[tid] + u.lg.xs2[tid + 128]) * (1.f / (float)T_);
        __syncthreads();
        float lg = 0.f;
        if (wf32) {
            const float* w = (const float*)Wq + (size_t)d0 * QDIM_ + tid;
            #pragma unroll 8
            for (int d = 0; d < 128; ++d) lg += u.lg.xs[d] * w[(size_t)d * QDIM_];
        } else {
            const unsigned short* w = (const unsigned short*)Wq + (size_t)d0 * QDIM_ + tid;
            #pragma unroll 8
            for (int d = 0; d < 128; ++d) lg += u.lg.xs[d] * b2f(w[(size_t)d * QDIM_]);
        }
        plog[((size_t)(b * 8 + dc)) * QDIM_ + tid] = lg;
        arrive(c + 1);
    } else if (blk < 128) {
        // ---- wdred slice (no wait): wdred[j][d] = sum_k Wd[j+8k][d]
        if (tid < 128) {
            int flat = (blk - 64) * 128 + tid;
            int j = flat >> 10, d = flat & (D_ - 1);
            float s = 0.f;
            if (wf32) {
                const float* w = (const float*)Wd;
                #pragma unroll 8
                for (int k = 0; k < 32; ++k) s += w[(size_t)(j + 8 * k) * D_ + d];
            } else {
                const unsigned short* w = (const unsigned short*)Wd;
                #pragma unroll 8
                for (int k = 0; k < 32; ++k) s += b2f(w[(size_t)(j + 8 * k) * D_ + d]);
            }
            wdred[flat] = s;
        }
        arrive(c + 3);
    } else if (blk < 136) {
        // ---- softmax + clamped amp-means: b = blk-128
        wait_for(c + 1, 64);
        int b = blk - 128;
        float lg = wf32 ? ((const float*)bq)[tid] : b2f(((const unsigned short*)bq)[tid]);
        for (int dc = 0; dc < 8; ++dc) lg += plog[((size_t)(b * 8 + dc)) * QDIM_ + tid];
        float mx = blockMax(lg, u.sm.buf);
        float e = __expf(lg - mx);
        float ss = blockSum(e, u.sm.buf);
        u.sm.qa[tid] = e / ss;
        __syncthreads();
        if (tid < 16) {
            int q = tid >> 1, bit = tid & 1;
            int sw = 1 << (7 - q);
            float acc = 0.f;
            for (int i = 0; i < sw; ++i) {
                int idx = 2 * sw * i + bit * sw;
                if (idx > QDIM_ - 1) idx = QDIM_ - 1;
                acc += u.sm.qa[idx];
            }
            float m = acc / (float)sw;
            if (bit == 0) sm0m[b * 8 + q] = m; else sm1m[b * 8 + q] = m;
        }
        arrive(c + 2);
    } else if (blk >= 192 && blk < 256) {
        // ---- MPS contraction + feats: slot s = blk-192; cores read via L1.
        int s = blk - 192;
        MpsSh& M = u.mps;
        // stage tiny first/last cores + m-means; wait for m first (cheap)
        wait_for(c + 2, 8);
        if (wf32) {
            if (tid < 64) {
                M.lcf[tid] = ((const float*)cf)[s * 64 + tid];
                M.lcl[tid] = ((const float*)cl)[s * 64 + tid];
            }
        } else {
            if (tid < 64) {
                M.lcf[tid] = b2f(((const unsigned short*)cf)[s * 64 + tid]);
                M.lcl[tid] = b2f(((const unsigned short*)cl)[s * 64 + tid]);
            }
        }
        if (tid < 64) { M.lm0[tid] = sm0m[tid]; M.lm1[tid] = sm1m[tid]; }
        __syncthreads();

        // feats: mid-core sums straight from global (L1/L2-cached)
        {
            float v = (tid < 64) ? M.lcf[tid] : 0.f;
            float f0 = blockSum(v, M.buf) * (1.f / 64.f);
            float fj[6];
            for (int j = 0; j < 6; ++j) {
                float a = 0.f;
                if (wf32) {
                    const float* pcm = (const float*)cm + (size_t)s * 12288 + j * 2048;
                    for (int k = tid; k < 2048; k += 256) a += pcm[k];
                } else {
                    const unsigned short* pcm = (const unsigned short*)cm + (size_t)s * 12288 + j * 2048;
                    for (int k = tid; k < 2048; k += 256) a += b2f(pcm[k]);
                }
                fj[j] = blockSum(a, M.buf) * (1.f / 2048.f);
            }
            float w = (tid < 64) ? M.lcl[tid] : 0.f;
            float fl = blockSum(w, M.buf) * (1.f / 64.f);
            if (tid == 0) {
                feats[s * 8 + 0] = f0;
                #pragma unroll
                for (int j = 0; j < 6; ++j) feats[s * 8 + 1 + j] = fj[j];
                feats[s * 8 + 7] = fl;
            }
        }

        int b = tid >> 5, r = tid & 31;
        M.res[b][r] = M.lm0[b * 8 + 0] * M.lcf[r] + M.lm1[b * 8 + 0] * M.lcf[32 + r];
        __syncthreads();
        for (int q = 1; q <= 6; ++q) {
            float m0 = M.lm0[b * 8 + q], m1 = M.lm1[b * 8 + q];
            float acc = 0.f;
            if (wf32) {
                const float* C = (const float*)cm + (size_t)s * 12288 + (q - 1) * 2048;
                #pragma unroll 8
                for (int l = 0; l < 32; ++l)
                    acc += M.res[b][l] * (m0 * C[l * 64 + r] + m1 * C[l * 64 + 32 + r]);
            } else {
                const unsigned short* C = (const unsigned short*)cm + (size_t)s * 12288 + (q - 1) * 2048;
                #pragma unroll 8
                for (int l = 0; l < 32; ++l)
                    acc += M.res[b][l] * (m0 * b2f(C[l * 64 + r]) + m1 * b2f(C[l * 64 + 32 + r]));
            }
            M.nres[b][r] = acc;
            __syncthreads();
            M.res[b][r] = M.nres[b][r];
            __syncthreads();
        }
        {
            float m0 = M.lm0[b * 8 + 7], m1 = M.lm1[b * 8 + 7];
            float p = M.res[b][r] * (m0 * M.lcl[r * 2] + m1 * M.lcl[r * 2 + 1]);
            #pragma unroll
            for (int off = 16; off > 0; off >>= 1) p += __shfl_xor(p, off, 64);
            if (r == 0) ovl[b * 64 + s] = p;
        }
        arrive(c + 3);
    } else if (blk >= 256 && blk < 264) {
        // ---- attention softmax + g + read_proj: b = blk-256
        wait_for(c + 3, 128);       // 64 MPS + 64 wdred arrivals
        int b = blk - 256;
        if (tid < 64) {
            float o = ovl[b * 64 + tid];
            float mx = o;
            #pragma unroll
            for (int off = 32; off > 0; off >>= 1) mx = fmaxf(mx, __shfl_xor(mx, off, 64));
            float e = __expf(o - mx);
            float se = e;
            #pragma unroll
            for (int off = 32; off > 0; off >>= 1) se += __shfl_xor(se, off, 64);
            u.att.att[tid] = e / se;
        }
        __syncthreads();
        if (tid < 8) {
            float g = 0.f;
            for (int s2 = 0; s2 < S_; ++s2) g += u.att.att[s2] * feats[s2 * 8 + tid];
            u.att.g[tid] = g;
        }
        __syncthreads();
        #pragma unroll
        for (int i = 0; i < 4; ++i) {
            int d = tid + i * 256;
            float a = wf32 ? ((const float*)bd)[d] : b2f(((const unsigned short*)bd)[d]);
            #pragma unroll
            for (int j = 0; j < 8; ++j) a += u.att.g[j] * wdred[(size_t)j * D_ + d];
            read_proj[(size_t)b * D_ + d] = a;
        }
    }
}

// K2: out = x + read_proj[b,:] broadcast. grid = 16384 -> high occupancy
// streaming. Output dtype follows x's dtype. Kernel boundary is the full-grid
// dependency on read_proj.
__global__ __launch_bounds__(256)
void k_add(const void* __restrict__ x, const float* __restrict__ rp,
           void* __restrict__ out) {
    __shared__ int cnt;
    bool xf32 = detect_f32((const unsigned short*)x, 100, 130, &cnt);
    size_t base = (((size_t)blockIdx.x) * 256 + threadIdx.x) * 8;
    int b = (int)(base >> 22);          // T_*D_ = 2^22
    int d = (int)(base & (D_ - 1));
    const float* r = rp + (size_t)b * D_ + d;
    f32x4 r0 = *reinterpret_cast<const f32x4*>(r);
    f32x4 r1 = *reinterpret_cast<const f32x4*>(r + 4);
    if (xf32) {
        const float* px = (const float*)x + base;
        f32x4 v0 = *reinterpret_cast<const f32x4*>(px);
        f32x4 v1 = *reinterpret_cast<const f32x4*>(px + 4);
        f32x4 o0 = v0 + r0;
        f32x4 o1 = v1 + r1;
        float* po = (float*)out + base;
        *reinterpret_cast<f32x4*>(po) = o0;
        *reinterpret_cast<f32x4*>(po + 4) = o1;
    } else {
        u16x8 v = *reinterpret_cast<const u16x8*>((const unsigned short*)x + base);
        u16x8 o;
        #pragma unroll
        for (int k = 0; k < 4; ++k) o[k] = f2b(b2f(v[k]) + r0[k]);
        #pragma unroll
        for (int k = 0; k < 4; ++k) o[4 + k] = f2b(b2f(v[4 + k]) + r1[k]);
        *reinterpret_cast<u16x8*>((unsigned short*)out + base) = o;
    }
}

extern "C" void kernel_launch(void* const* d_in, const int* in_sizes, int n_in,
                              void* d_out, int out_size, void* d_ws, size_t ws_size,
                              hipStream_t stream) {
    const void* x  = d_in[0];
    const void* Wq = d_in[1];
    const void* bq = d_in[2];
    const void* Wd = d_in[3];
    const void* bd = d_in[4];
    const void* cf = d_in[5];
    const void* cm = d_in[6];
    const void* cl = d_in[7];

    float* ws        = (float*)d_ws;
    float* partials  = ws;                        // 524288 f32 (2 MB)
    float* plog      = partials + 524288;         // 16384
    float* sm0m      = plog + 16384;              // 64
    float* sm1m      = sm0m + 64;                 // 64
    float* feats     = sm1m + 64;                 // 512
    float* ovl       = feats + 512;               // 512
    float* read_proj = ovl + 512;                 // 8192
    float* wdred     = read_proj + 8192;          // 8192
    int*   c         = (int*)(wdred + 8192);      // 8 ints (4 used)

    hipMemsetAsync(c, 0, 32, stream);
    k_main<<<NBLK, 256, 0, stream>>>(x, Wq, bq, Wd, bd, cf, cm, cl,
                                     partials, plog, sm0m, sm1m, feats, ovl,
                                     read_proj, wdred, c);
    k_add<<<(B_ * T_ * D_) / 2048, 256, 0, stream>>>(x, read_proj, d_out);
}

// Round 4
// 299.950 us; speedup vs baseline: 1.2182x; 1.2182x over previous
//
#include <hip/hip_runtime.h>
#include <hip/hip_bf16.h>

// Problem constants
#define B_    8
#define T_    4096
#define D_    1024
#define S_    64
#define NQ_   8
#define QDIM_ 256
#define TB_   64            // t-rows per partial-sum block
#define NTC_  (T_/TB_)      // 64 chunks

typedef __attribute__((ext_vector_type(4))) unsigned short u16x4;
typedef __attribute__((ext_vector_type(8))) unsigned short u16x8;
typedef __attribute__((ext_vector_type(4))) float f32x4;

__device__ __forceinline__ float b2f(unsigned short u) {
    union { unsigned int i; float f; } v; v.i = ((unsigned int)u) << 16; return v.f;
}
__device__ __forceinline__ unsigned short f2b(float f) {
    __hip_bfloat16 h = __float2bfloat16(f);   // RNE
    return *reinterpret_cast<unsigned short*>(&h);
}

// LDS-tree block reduction, 256 threads, buf is 256-float scratch.
__device__ __forceinline__ float blockSum(float v, float* buf) {
    int tid = threadIdx.x;
    buf[tid] = v; __syncthreads();
    #pragma unroll
    for (int s = 128; s > 0; s >>= 1) { if (tid < s) buf[tid] += buf[tid + s]; __syncthreads(); }
    float r = buf[0]; __syncthreads();
    return r;
}

// Per-block dtype detection: 256 threads sample 256 u16 words (same 512 B for
// every block -> L2/L3 broadcast). bf16 buffers decode ~256/256 plausible; the
// lo-halves of f32 words have random mantissa bits -> ~143/256.
__device__ __forceinline__ bool detect_f32(const unsigned short* __restrict__ p,
                                           unsigned elo, unsigned ehi, int* cnt) {
    int tid = threadIdx.x;
    if (tid == 0) *cnt = 0;
    __syncthreads();
    unsigned short u = p[tid];
    unsigned e = (u >> 7) & 0xFF;
    bool ok = ((u & 0x7FFF) == 0) || (e >= elo && e <= ehi);
    unsigned long long bm = __ballot(ok);
    if ((tid & 63) == 0) atomicAdd(cnt, (int)__popcll(bm));
    __syncthreads();
    bool isf32 = (*cnt < 200);
    __syncthreads();
    return isf32;
}

// K1: partial column sums of x. partials[tc][b][d] f32. grid = 512, 256 thr.
__global__ __launch_bounds__(256)
void k_colsum(const void* __restrict__ x, float* __restrict__ partials) {
    __shared__ int cnt;
    bool xf32 = detect_f32((const unsigned short*)x, 100, 130, &cnt); // |v| in [2^-27,16)
    int blk = blockIdx.x;
    int b  = blk >> 6;
    int tc = blk & 63;
    int tid = threadIdx.x;
    size_t base = ((size_t)(b * T_ + tc * TB_)) * D_ + tid * 4;
    float a0 = 0.f, a1 = 0.f, a2 = 0.f, a3 = 0.f;
    if (xf32) {
        const float* px = (const float*)x + base;
        #pragma unroll 8
        for (int i = 0; i < TB_; ++i) {
            f32x4 v = *reinterpret_cast<const f32x4*>(px + (size_t)i * D_);
            a0 += v[0]; a1 += v[1]; a2 += v[2]; a3 += v[3];
        }
    } else {
        const unsigned short* px = (const unsigned short*)x + base;
        #pragma unroll 8
        for (int i = 0; i < TB_; ++i) {
            u16x4 v = *reinterpret_cast<const u16x4*>(px + (size_t)i * D_);
            a0 += b2f(v[0]); a1 += b2f(v[1]); a2 += b2f(v[2]); a3 += b2f(v[3]);
        }
    }
    float* dst = partials + ((size_t)(tc * B_ + b)) * D_ + tid * 4;
    f32x4 r; r[0] = a0; r[1] = a1; r[2] = a2; r[3] = a3;
    *reinterpret_cast<f32x4*>(dst) = r;
}

// K2: blocks 0-63: finish xs + partial logits; blocks 64-127: wdred slices.
__global__ __launch_bounds__(256)
void k_logits(const void* __restrict__ Wq, const void* __restrict__ Wd,
              const float* __restrict__ partials, float* __restrict__ plog,
              float* __restrict__ wdred) {
    __shared__ float xs2[256];
    __shared__ float xs[128];
    __shared__ int cnt;
    const int blk = blockIdx.x;
    const int tid = threadIdx.x;
    bool wf32 = detect_f32((const unsigned short*)Wq, 96, 126, &cnt); // |v| in [2^-31,0.5)

    if (blk < 64) {
        int b = blk >> 3, dc = blk & 7;
        int d0 = dc * 128;
        float a = 0.f;
        for (int tc = (tid >> 7); tc < NTC_; tc += 2)
            a += partials[((size_t)(tc * B_ + b)) * D_ + d0 + (tid & 127)];
        xs2[tid] = a;
        __syncthreads();
        if (tid < 128) xs[tid] = (xs2[tid] + xs2[tid + 128]) * (1.f / (float)T_);
        __syncthreads();
        float lg = 0.f;
        if (wf32) {
            const float* w = (const float*)Wq + (size_t)d0 * QDIM_ + tid;
            #pragma unroll 8
            for (int d = 0; d < 128; ++d) lg += xs[d] * w[(size_t)d * QDIM_];
        } else {
            const unsigned short* w = (const unsigned short*)Wq + (size_t)d0 * QDIM_ + tid;
            #pragma unroll 8
            for (int d = 0; d < 128; ++d) lg += xs[d] * b2f(w[(size_t)d * QDIM_]);
        }
        plog[((size_t)(b * 8 + dc)) * QDIM_ + tid] = lg;
    } else {
        // wdred[j][d] = sum_{k<32} Wd[j+8k][d]  (slot_values tiling collapses Wd)
        if (tid < 128) {
            int flat = (blk - 64) * 128 + tid;
            int j = flat >> 10, d = flat & (D_ - 1);
            float s = 0.f;
            if (wf32) {
                const float* w = (const float*)Wd;
                #pragma unroll 8
                for (int k = 0; k < 32; ++k) s += w[(size_t)(j + 8 * k) * D_ + d];
            } else {
                const unsigned short* w = (const unsigned short*)Wd;
                #pragma unroll 8
                for (int k = 0; k < 32; ++k) s += b2f(w[(size_t)(j + 8 * k) * D_ + d]);
            }
            wdred[flat] = s;
        }
    }
}

// K3: grid = 64 (one block per slot). Each block REDUNDANTLY computes
// softmax+amp-means for all 8 batches (half-wave shfl reductions, no global
// round-trip), then its slot's MPS contraction + feats. No cross-block sync.
__global__ __launch_bounds__(256)
void k_mps(const void* __restrict__ Wq, const void* __restrict__ bq,
           const void* __restrict__ cf, const void* __restrict__ cm,
           const void* __restrict__ cl, const float* __restrict__ plog,
           float* __restrict__ feats, float* __restrict__ ovl) {
    __shared__ float qa[8 * QDIM_];       // 8 KB
    __shared__ float lcm[6 * 2048];       // 48 KB
    __shared__ float lcf[64];
    __shared__ float lcl[64];
    __shared__ float res[8][33];
    __shared__ float nres[8][33];
    __shared__ float lm0[64], lm1[64];
    __shared__ float buf[256];
    __shared__ int cnt;
    const int s = blockIdx.x;
    const int tid = threadIdx.x;
    bool wf32 = detect_f32((const unsigned short*)Wq, 96, 126, &cnt);

    // ---- softmax over logits, per batch, half-wave parallel (b = tid>>5)
    {
        int b = tid >> 5, l = tid & 31;
        float lg8[8];
        #pragma unroll
        for (int i = 0; i < 8; ++i) {
            int j = i * 32 + l;
            float v = wf32 ? ((const float*)bq)[j] : b2f(((const unsigned short*)bq)[j]);
            #pragma unroll
            for (int dc = 0; dc < 8; ++dc) v += plog[((size_t)(b * 8 + dc)) * QDIM_ + j];
            lg8[i] = v;
        }
        float mx = lg8[0];
        #pragma unroll
        for (int i = 1; i < 8; ++i) mx = fmaxf(mx, lg8[i]);
        #pragma unroll
        for (int off = 16; off > 0; off >>= 1) mx = fmaxf(mx, __shfl_xor(mx, off, 64));
        float ss = 0.f, e8[8];
        #pragma unroll
        for (int i = 0; i < 8; ++i) { e8[i] = __expf(lg8[i] - mx); ss += e8[i]; }
        #pragma unroll
        for (int off = 16; off > 0; off >>= 1) ss += __shfl_xor(ss, off, 64);
        float inv = 1.f / ss;
        #pragma unroll
        for (int i = 0; i < 8; ++i) qa[b * QDIM_ + i * 32 + l] = e8[i] * inv;
    }
    __syncthreads();
    // ---- clamped amp-means -> lm0/lm1 in LDS
    if (tid < 128) {
        int bb = tid >> 4, q = (tid >> 1) & 7, bit = tid & 1;
        int sw = 1 << (7 - q);
        float acc = 0.f;
        for (int i = 0; i < sw; ++i) {
            int idx = 2 * sw * i + bit * sw;
            if (idx > QDIM_ - 1) idx = QDIM_ - 1;
            acc += qa[bb * QDIM_ + idx];
        }
        float m = acc / (float)sw;
        if (bit == 0) lm0[bb * 8 + q] = m; else lm1[bb * 8 + q] = m;
    }

    // ---- stage slot cores to LDS
    if (wf32) {
        const float* pcm = (const float*)cm + (size_t)s * 12288;
        for (int i = tid; i < 12288; i += 256) lcm[i] = pcm[i];
        if (tid < 64) {
            lcf[tid] = ((const float*)cf)[s * 64 + tid];
            lcl[tid] = ((const float*)cl)[s * 64 + tid];
        }
    } else {
        const unsigned short* pcm = (const unsigned short*)cm + (size_t)s * 12288;
        for (int i = tid; i < 12288; i += 256) lcm[i] = b2f(pcm[i]);
        if (tid < 64) {
            lcf[tid] = b2f(((const unsigned short*)cf)[s * 64 + tid]);
            lcl[tid] = b2f(((const unsigned short*)cl)[s * 64 + tid]);
        }
    }
    __syncthreads();

    // ---- feats from LDS
    {
        float v = (tid < 64) ? lcf[tid] : 0.f;
        float f0 = blockSum(v, buf) * (1.f / 64.f);
        float fj[6];
        for (int j = 0; j < 6; ++j) {
            float a = 0.f;
            for (int k = tid; k < 2048; k += 256) a += lcm[j * 2048 + k];
            fj[j] = blockSum(a, buf) * (1.f / 2048.f);
        }
        float w = (tid < 64) ? lcl[tid] : 0.f;
        float fl = blockSum(w, buf) * (1.f / 64.f);
        if (tid == 0) {
            feats[s * 8 + 0] = f0;
            #pragma unroll
            for (int j = 0; j < 6; ++j) feats[s * 8 + 1 + j] = fj[j];
            feats[s * 8 + 7] = fl;
        }
    }

    // ---- MPS contraction: b = tid>>5, r = tid&31
    int b = tid >> 5, r = tid & 31;
    res[b][r] = lm0[b * 8 + 0] * lcf[r] + lm1[b * 8 + 0] * lcf[32 + r];
    __syncthreads();
    for (int q = 1; q <= 6; ++q) {
        float m0 = lm0[b * 8 + q], m1 = lm1[b * 8 + q];
        const float* C = &lcm[(q - 1) * 2048];
        float acc = 0.f;
        #pragma unroll 8
        for (int l = 0; l < 32; ++l)
            acc += res[b][l] * (m0 * C[l * 64 + r] + m1 * C[l * 64 + 32 + r]);
        nres[b][r] = acc;
        __syncthreads();
        res[b][r] = nres[b][r];
        __syncthreads();
    }
    {
        float m0 = lm0[b * 8 + 7], m1 = lm1[b * 8 + 7];
        float p = res[b][r] * (m0 * lcl[r * 2] + m1 * lcl[r * 2 + 1]);
        #pragma unroll
        for (int off = 16; off > 0; off >>= 1) p += __shfl_xor(p, off, 64);
        if (r == 0) ovl[b * 64 + s] = p;
    }
}

// K4: attention softmax + g + read_proj via wdred. grid = 8 (one block per b).
__global__ __launch_bounds__(256)
void k_attn(const void* __restrict__ Wq, const void* __restrict__ bd,
            const float* __restrict__ ovl, const float* __restrict__ feats,
            const float* __restrict__ wdred, float* __restrict__ read_proj) {
    __shared__ float att[S_];
    __shared__ float gl[NQ_];
    __shared__ int cnt;
    const int b = blockIdx.x;
    const int tid = threadIdx.x;
    bool wf32 = detect_f32((const unsigned short*)Wq, 96, 126, &cnt);

    if (tid < 64) {
        float o = ovl[b * 64 + tid];
        float mx = o;
        #pragma unroll
        for (int off = 32; off > 0; off >>= 1) mx = fmaxf(mx, __shfl_xor(mx, off, 64));
        float e = __expf(o - mx);
        float se = e;
        #pragma unroll
        for (int off = 32; off > 0; off >>= 1) se += __shfl_xor(se, off, 64);
        att[tid] = e / se;
    }
    __syncthreads();
    if (tid < 8) {
        float g = 0.f;
        for (int s2 = 0; s2 < S_; ++s2) g += att[s2] * feats[s2 * 8 + tid];
        gl[tid] = g;
    }
    __syncthreads();
    #pragma unroll
    for (int i = 0; i < 4; ++i) {
        int d = tid + i * 256;
        float a = wf32 ? ((const float*)bd)[d] : b2f(((const unsigned short*)bd)[d]);
        #pragma unroll
        for (int j = 0; j < 8; ++j) a += gl[j] * wdred[(size_t)j * D_ + d];
        read_proj[(size_t)b * D_ + d] = a;
    }
}

// K5: out = x + read_proj[b,:] broadcast. grid = 16384, high-occupancy stream.
__global__ __launch_bounds__(256)
void k_add(const void* __restrict__ x, const float* __restrict__ rp,
           void* __restrict__ out) {
    __shared__ int cnt;
    bool xf32 = detect_f32((const unsigned short*)x, 100, 130, &cnt);
    size_t base = (((size_t)blockIdx.x) * 256 + threadIdx.x) * 8;
    int b = (int)(base >> 22);          // T_*D_ = 2^22
    int d = (int)(base & (D_ - 1));
    const float* r = rp + (size_t)b * D_ + d;
    f32x4 r0 = *reinterpret_cast<const f32x4*>(r);
    f32x4 r1 = *reinterpret_cast<const f32x4*>(r + 4);
    if (xf32) {
        const float* px = (const float*)x + base;
        f32x4 v0 = *reinterpret_cast<const f32x4*>(px);
        f32x4 v1 = *reinterpret_cast<const f32x4*>(px + 4);
        f32x4 o0 = v0 + r0;
        f32x4 o1 = v1 + r1;
        float* po = (float*)out + base;
        *reinterpret_cast<f32x4*>(po) = o0;
        *reinterpret_cast<f32x4*>(po + 4) = o1;
    } else {
        u16x8 v = *reinterpret_cast<const u16x8*>((const unsigned short*)x + base);
        u16x8 o;
        #pragma unroll
        for (int k = 0; k < 4; ++k) o[k] = f2b(b2f(v[k]) + r0[k]);
        #pragma unroll
        for (int k = 0; k < 4; ++k) o[4 + k] = f2b(b2f(v[4 + k]) + r1[k]);
        *reinterpret_cast<u16x8*>((unsigned short*)out + base) = o;
    }
}

extern "C" void kernel_launch(void* const* d_in, const int* in_sizes, int n_in,
                              void* d_out, int out_size, void* d_ws, size_t ws_size,
                              hipStream_t stream) {
    const void* x  = d_in[0];
    const void* Wq = d_in[1];
    const void* bq = d_in[2];
    const void* Wd = d_in[3];
    const void* bd = d_in[4];
    const void* cf = d_in[5];
    const void* cm = d_in[6];
    const void* cl = d_in[7];

    float* ws        = (float*)d_ws;
    float* partials  = ws;                        // 524288 f32 (2 MB)
    float* plog      = partials + 524288;         // 16384
    float* feats     = plog + 16384;              // 512
    float* ovl       = feats + 512;               // 512
    float* read_proj = ovl + 512;                 // 8192
    float* wdred     = read_proj + 8192;          // 8192

    k_colsum<<<B_ * NTC_, 256, 0, stream>>>(x, partials);
    k_logits<<<128, 256, 0, stream>>>(Wq, Wd, partials, plog, wdred);
    k_mps<<<S_, 256, 0, stream>>>(Wq, bq, cf, cm, cl, plog, feats, ovl);
    k_attn<<<B_, 256, 0, stream>>>(Wq, bd, ovl, feats, wdred, read_proj);
    k_add<<<(B_ * T_ * D_) / 2048, 256, 0, stream>>>(x, read_proj, d_out);
}